// Round 17
// baseline (786.786 us; speedup 1.0000x reference)
//
#include <hip/hip_runtime.h>
#include <hip/hip_bf16.h>

// B=8, T=2048, D=2048.
//   avg = cumsum(x, axis=T) / (t+1)
//   gates = concat(x, avg) @ W^T + b    (W: [4096][4096])
//   out0 = sig(gates[:, :2048]) * x + sig(gates[:, 2048:]) * avg
// outputs: [out0 fp32] ++ [avg fp32]

#define Bb 8
#define Tt 2048
#define Dd 2048
#define Mm (Bb * Tt)       // 16384
#define Kk 4096
#define NC 32
#define CT 64

typedef __bf16 bf16x8 __attribute__((ext_vector_type(8)));
typedef float f32x16 __attribute__((ext_vector_type(16)));

__device__ __forceinline__ void gload16(const void* g, void* l) {
    __builtin_amdgcn_global_load_lds(
        (const __attribute__((address_space(1))) unsigned int*)g,
        (__attribute__((address_space(3))) unsigned int*)l, 16, 0, 0);
}

// ---------------- K1: W fp32 -> bf16 ----------------
__global__ void wconv_kernel(const float* __restrict__ W,
                             unsigned short* __restrict__ Wb, long n) {
    long i = ((long)blockIdx.x * blockDim.x + threadIdx.x) * 4;
    long stride = (long)gridDim.x * blockDim.x * 4;
    for (; i < n; i += stride) {
        float4 v = *(const float4*)(W + i);
        __hip_bfloat16 a = __float2bfloat16(v.x);
        __hip_bfloat16 b = __float2bfloat16(v.y);
        __hip_bfloat16 c = __float2bfloat16(v.z);
        __hip_bfloat16 d = __float2bfloat16(v.w);
        ushort4 u;
        u.x = *(unsigned short*)&a; u.y = *(unsigned short*)&b;
        u.z = *(unsigned short*)&c; u.w = *(unsigned short*)&d;
        *(ushort4*)(Wb + i) = u;
    }
}

// ---------------- K2: per-chunk sums + emit bf16 x-half of Gin --------------
__global__ void ksum_kernel(const float* __restrict__ X, float* __restrict__ S,
                            unsigned short* __restrict__ Gin) {
    int d = blockIdx.y * 256 + threadIdx.x;
    int bc = blockIdx.x;
    int b = bc >> 5, c = bc & 31;
    const float* p = X + ((long)(b * Tt + c * CT)) * Dd + d;
    long row = (long)b * Tt + c * CT;
    float s = 0.f;
#pragma unroll 8
    for (int t = 0; t < CT; ++t) {
        float x = p[(long)t * Dd];
        s += x;
        __hip_bfloat16 xb = __float2bfloat16(x);
        Gin[(row + t) * 4096 + d] = *(unsigned short*)&xb;
    }
    S[(long)bc * Dd + d] = s;
}

// ---------------- K3: scan (bf16 x) + emit avg fp32 + Gin avg-half ----------
__global__ void kscan_kernel(const unsigned short* __restrict__ Ginx,
                             const float* __restrict__ S,
                             float* __restrict__ AVG, unsigned short* __restrict__ Gin) {
    int d = blockIdx.y * 256 + threadIdx.x;
    int bc = blockIdx.x;
    int b = bc >> 5, c = bc & 31;
    const float* Sp = S + (long)(b * NC) * Dd + d;
    float run = 0.f;
    for (int cc = 0; cc < c; ++cc) run += Sp[(long)cc * Dd];
    long row = (long)b * Tt + c * CT;
    for (int tt = 0; tt < CT; ++tt) {
        long r = row + tt;
        union { unsigned int u; float f; } cx;
        cx.u = ((unsigned int)Ginx[r * 4096 + d]) << 16;
        run += cx.f;
        float av = run / (float)(c * CT + tt + 1);
        AVG[r * Dd + d] = av;
        __hip_bfloat16 ab = __float2bfloat16(av);
        Gin[r * 4096 + 2048 + d] = *(unsigned short*)&ab;
    }
}

// ---------------- K4: 8-wave 256x(128d x 2 gates), BK=64, 32x32x16 ----------
// R8's sync skeleton byte-for-byte (counted vmcnt(2)/(4), 2 barriers/tile,
// pipelined read batches), with:
//  * mfma_f32_32x32x16_bf16 (MFMA floor 2483 -> 2065 cyc/tile; R3-verified
//    fragment + C/D layouts, R12-verified epilogue)
//  * chunk-transposed LDS lines: each 8KB line = [chunk c:4][row R:128] x16B.
//    Frag reads are 512B-contiguous per 32-lane half -> minimal bank access,
//    NO xor swizzle (vs R12's 5e7 conflict cycles). Staging keeps a LINEAR
//    dest (global_load_lds) — the transpose lives in the SOURCE address.
// Buf (64KB): [A0 8K][A1 8K][B0 8K][B1 8K] kk0, same +32768 kk1.
//   A0 = rows m0..+127, A1 = +128; B0 = W rows n0..+127 (gate i),
//   B1 = W rows 2048+n0..+127 (gate f).
// K-steps s=0..3 (16 k each): offset = (s>>1)*32768 + (s&1)*4096 (+lk*2048).
// vm FIFO: entry 4 outstanding (kk1(t)); PH0 +2 -> vmcnt(2) drains kk1(t);
// PH1 +2, PH2 +2, PH3 +2 -> vmcnt(4) drains kk0(t+1); leaves kk1(t+1).
#define MFMA32(va, vb, c_) c_ = __builtin_amdgcn_mfma_f32_32x32x16_bf16(va, vb, c_, 0, 0, 0)
#define SBAR __builtin_amdgcn_s_barrier()
#define SCHB __builtin_amdgcn_sched_barrier(0)
#define LGKM0 do { asm volatile("s_waitcnt lgkmcnt(0)" ::: "memory"); SCHB; } while (0)

#define READ6(S_, off_)                                                         \
    S_##a0 = *(const bf16x8*)(rAc + (off_));                                    \
    S_##a1 = *(const bf16x8*)(rAc + (off_) + 512);                              \
    S_##a2 = *(const bf16x8*)(rAc + (off_) + 1024);                             \
    S_##a3 = *(const bf16x8*)(rAc + (off_) + 1536);                             \
    S_##b0 = *(const bf16x8*)(rBc + (off_));                                    \
    S_##b1 = *(const bf16x8*)(rBc + (off_) + 8192);

#define CLUST(S_)                                                               \
    __builtin_amdgcn_s_setprio(1);                                              \
    MFMA32(S_##a0, S_##b0, acc[0][0]); MFMA32(S_##a0, S_##b1, acc[0][1]);       \
    MFMA32(S_##a1, S_##b0, acc[1][0]); MFMA32(S_##a1, S_##b1, acc[1][1]);       \
    MFMA32(S_##a2, S_##b0, acc[2][0]); MFMA32(S_##a2, S_##b1, acc[2][1]);       \
    MFMA32(S_##a3, S_##b0, acc[3][0]); MFMA32(S_##a3, S_##b1, acc[3][1]);       \
    __builtin_amdgcn_s_setprio(0);

#define TILE32R(t_, bb_, STG_, VM_, VB_)                                        \
  {                                                                             \
    char* nb_ = ldsb + ((bb_) ^ 65536) + woff;                                  \
    const long ko_ = ((long)(t_) + 1) * 128;                                    \
    /* tile start: R0 = kstep0; stage Akk0(t+1) */                              \
    READ6(p, (bb_))                                                             \
    if (STG_) { gload16(gA0 + ko_, nb_); gload16(gA1 + ko_, nb_ + 8192); }      \
    LGKM0;                                      /* R0 ready */                  \
    /* PH0: issue R1 = kstep1; MFMA kstep0; mid vmcnt+barrier */                \
    READ6(q, (bb_) + 4096)                                                      \
    SCHB;                                                                       \
    CLUST(p)                                                                    \
    SCHB;                                                                       \
    asm volatile("s_waitcnt vmcnt(" #VM_ ")" ::: "memory");                     \
    SBAR; SCHB;                                 /* kk1(t) visible */            \
    LGKM0;                                      /* R1 ready */                  \
    /* PH1: issue R2 = kstep2 (kk1); stage Bkk0(t+1); MFMA kstep1 */            \
    READ6(p, (bb_) + 32768)                                                     \
    if (STG_) { gload16(gB0 + ko_, nb_ + 16384); gload16(gB1 + ko_, nb_ + 24576); } \
    SCHB;                                                                       \
    CLUST(q)                                                                    \
    SCHB;                                                                       \
    LGKM0;                                      /* R2 ready */                  \
    /* PH2: issue R3 = kstep3; stage Akk1(t+1); MFMA kstep2 */                  \
    READ6(q, (bb_) + 36864)                                                     \
    if (STG_) { gload16(gA0 + ko_ + 64, nb_ + 32768); gload16(gA1 + ko_ + 64, nb_ + 40960); } \
    SCHB;                                                                       \
    CLUST(p)                                                                    \
    SCHB;                                                                       \
    LGKM0;                                      /* R3 ready */                  \
    /* PH3: stage Bkk1(t+1); MFMA kstep3; boundary */                           \
    if (STG_) { gload16(gB0 + ko_ + 64, nb_ + 49152); gload16(gB1 + ko_ + 64, nb_ + 57344); } \
    SCHB;                                                                       \
    CLUST(q)                                                                    \
    SCHB;                                                                       \
    asm volatile("s_waitcnt vmcnt(" #VB_ ")" ::: "memory");                     \
    SBAR; SCHB;                                 /* kk0(t+1) visible */          \
  }

__global__ __launch_bounds__(512, 1) void gemm32r2_kernel(
    const unsigned short* __restrict__ Gin,  // [16384][4096] bf16
    const unsigned short* __restrict__ Wb,   // [4096][4096] bf16
    const float* __restrict__ bias,          // [4096]
    float* __restrict__ OUT)                 // [16384][2048]
{
    __shared__ __attribute__((aligned(128))) char lds[131072]; // 2 x 64KB
    char* ldsb = (char*)lds;

    const int tid = threadIdx.x;
    const int w = tid >> 6, l = tid & 63;
    const int wm = w >> 2, wn = w & 3;       // 2(M) x 4(N) waves
    const int la = l & 31;                   // fragment row/col within 32
    const int lk = l >> 5;                   // k half-group
    const int woff = w * 1024;

    // Batch-aware mapping (FETCH-proven): 256-block rounds = 16 m-tiles x
    // 16 n-tiles (A 32MB + W 32MB < L3); per XCD 2 n-tiles (B panel -> L2).
    const int bid = blockIdx.x;
    const int batch = bid >> 8;
    const int rr = bid & 255;
    const int xcd = rr & 7;
    const int j = rr >> 3;
    const int nt = xcd * 2 + (j >> 4);
    const int mt = batch * 16 + (j & 15);
    const long m0 = (long)mt * 256;
    const int n0 = nt * 128;

    // ---- staging source (chunk-transposed): thread tid loads row tid&127,
    //      16B-chunk tid>>7 of each 8KB line; dest is LINEAR (tid*16).
    const int r128 = tid & 127;
    const int ch = tid >> 7;                  // 0..3
    const char* gA0 = (const char*)Gin + (m0 + r128) * 8192 + ch * 16;
    const char* gA1 = gA0 + 128 * 8192;
    const char* gB0 = (const char*)Wb + ((long)(n0 + r128)) * 8192 + ch * 16;
    const char* gB1 = (const char*)Wb + ((long)(2048 + n0 + r128)) * 8192 + ch * 16;

    // ---- read bases: line layout [c:4][R:128] x 16B ----
    //   A frag (mi, s): wm*8192 + (s>>1)*32768 + (s&1)*4096 + lk*2048
    //                   + mi*512 + la*16
    const char* rAc = ldsb + wm * 8192 + lk * 2048 + la * 16;
    const char* rBc = ldsb + 16384 + lk * 2048 + (wn * 32 + la) * 16;

    f32x16 acc[4][2] = {};   // [mi][gate]: 0=input, 1=forget (same d cols)

    // operand sets
    bf16x8 pa0, pa1, pa2, pa3, pb0, pb1;
    bf16x8 qa0, qa1, qa2, qa3, qb0, qb1;

    // prologue: stage tile 0 into buf0 (A0,A1,B0,B1 kk0; then kk1)
    gload16(gA0,      ldsb + woff);
    gload16(gA1,      ldsb + 8192 + woff);
    gload16(gB0,      ldsb + 16384 + woff);
    gload16(gB1,      ldsb + 24576 + woff);
    gload16(gA0 + 64, ldsb + 32768 + woff);
    gload16(gA1 + 64, ldsb + 40960 + woff);
    gload16(gB0 + 64, ldsb + 49152 + woff);
    gload16(gB1 + 64, ldsb + 57344 + woff);
    asm volatile("s_waitcnt vmcnt(4)" ::: "memory");   // kk0 landed; kk1 in flight
    SBAR; SCHB;

#pragma unroll 1
    for (int t = 0; t < 62; t += 2) {     // stages tiles 1..62
        TILE32R(t,     0,     1, 2, 4)
        TILE32R(t + 1, 65536, 1, 2, 4)
    }
    TILE32R(62, 0,     1, 2, 4)           // stages tile 63
    TILE32R(63, 65536, 0, 0, 0)           // tail: drain

    // ---- fused epilogue (R3/R12-verified 32x32 C/D map; bf16 x/avg from Gin)
    // C/D: col = lane&31, row = (q&3) + 8*(q>>2) + 4*(lane>>5)
    const int d = n0 + wn * 32 + la;
    const float bi_ = bias[d];
    const float bf_ = bias[d + 2048];
#pragma unroll
    for (int mi = 0; mi < 4; ++mi) {
        const long rb = m0 + wm * 128 + mi * 32 + lk * 4;
        f32x16 ci = acc[mi][0];
        f32x16 cf = acc[mi][1];
#pragma unroll
        for (int qq = 0; qq < 16; ++qq) {
            long row = rb + (qq & 3) + 8 * (qq >> 2);
            unsigned int ux = Gin[row * 4096 + d];
            unsigned int ua = Gin[row * 4096 + 2048 + d];
            union { unsigned int u; float f; } cx, ca;
            cx.u = ux << 16; ca.u = ua << 16;
            float gi = ci[qq] + bi_;
            float gf = cf[qq] + bf_;
            float si = 1.f / (1.f + __expf(-gi));
            float sf = 1.f / (1.f + __expf(-gf));
            OUT[row * 2048 + d] = si * cx.f + sf * ca.f;
        }
    }
}

extern "C" void kernel_launch(void* const* d_in, const int* in_sizes, int n_in,
                              void* d_out, int out_size, void* d_ws, size_t ws_size,
                              hipStream_t stream) {
    const float* X = (const float*)d_in[0];     // layer_in [8][2048][2048]
    const float* W = (const float*)d_in[1];     // W_gate [4096][4096]
    const float* bias = (const float*)d_in[2];  // b_gate [4096]

    float* OUT = (float*)d_out;                 // gating_out
    float* AVG = OUT + (long)Mm * Dd;           // average_out

    char* ws = (char*)d_ws;
    unsigned short* Wb  = (unsigned short*)ws;                    // 33,554,432 B
    unsigned short* Gin = (unsigned short*)(ws + 33554432);       // 134,217,728 B
    float* S = (float*)(ws + 33554432 + 134217728);               // 2,097,152 B

    wconv_kernel<<<2048, 256, 0, stream>>>(W, Wb, (long)Kk * Kk);
    ksum_kernel<<<dim3(Bb * NC, Dd / 256), 256, 0, stream>>>(X, S, Gin);
    kscan_kernel<<<dim3(Bb * NC, Dd / 256), 256, 0, stream>>>(Gin, S, AVG, Gin);
    gemm32r2_kernel<<<1024, 512, 0, stream>>>(Gin, Wb, bias, OUT);
}

// Round 18
// 592.325 us; speedup vs baseline: 1.3283x; 1.3283x over previous
//
#include <hip/hip_runtime.h>
#include <hip/hip_bf16.h>

// B=8, T=2048, D=2048.
//   avg = cumsum(x, axis=T) / (t+1)
//   gates = concat(x, avg) @ W^T + b    (W: [4096][4096])
//   out0 = sig(gates[:, :2048]) * x + sig(gates[:, 2048:]) * avg
// outputs: [out0 fp32] ++ [avg fp32]

#define Bb 8
#define Tt 2048
#define Dd 2048
#define Mm (Bb * Tt)       // 16384
#define Kk 4096
#define NC 32
#define CT 64

typedef __bf16 bf16x8 __attribute__((ext_vector_type(8)));
typedef float f32x4 __attribute__((ext_vector_type(4)));

__device__ __forceinline__ void gload16(const void* g, void* l) {
    __builtin_amdgcn_global_load_lds(
        (const __attribute__((address_space(1))) unsigned int*)g,
        (__attribute__((address_space(3))) unsigned int*)l, 16, 0, 0);
}

// ---------------- K1: W fp32 -> bf16 ----------------
__global__ void wconv_kernel(const float* __restrict__ W,
                             unsigned short* __restrict__ Wb, long n) {
    long i = ((long)blockIdx.x * blockDim.x + threadIdx.x) * 4;
    long stride = (long)gridDim.x * blockDim.x * 4;
    for (; i < n; i += stride) {
        float4 v = *(const float4*)(W + i);
        __hip_bfloat16 a = __float2bfloat16(v.x);
        __hip_bfloat16 b = __float2bfloat16(v.y);
        __hip_bfloat16 c = __float2bfloat16(v.z);
        __hip_bfloat16 d = __float2bfloat16(v.w);
        ushort4 u;
        u.x = *(unsigned short*)&a; u.y = *(unsigned short*)&b;
        u.z = *(unsigned short*)&c; u.w = *(unsigned short*)&d;
        *(ushort4*)(Wb + i) = u;
    }
}

// ---------------- K2: per-chunk sums + emit bf16 x-half of Gin --------------
__global__ void ksum_kernel(const float* __restrict__ X, float* __restrict__ S,
                            unsigned short* __restrict__ Gin) {
    int d = blockIdx.y * 256 + threadIdx.x;
    int bc = blockIdx.x;
    int b = bc >> 5, c = bc & 31;
    const float* p = X + ((long)(b * Tt + c * CT)) * Dd + d;
    long row = (long)b * Tt + c * CT;
    float s = 0.f;
#pragma unroll 8
    for (int t = 0; t < CT; ++t) {
        float x = p[(long)t * Dd];
        s += x;
        __hip_bfloat16 xb = __float2bfloat16(x);
        Gin[(row + t) * 4096 + d] = *(unsigned short*)&xb;
    }
    S[(long)bc * Dd + d] = s;
}

// ---------------- K3: scan (bf16 x) + emit avg fp32 + Gin avg-half ----------
__global__ void kscan_kernel(const unsigned short* __restrict__ Ginx,
                             const float* __restrict__ S,
                             float* __restrict__ AVG, unsigned short* __restrict__ Gin) {
    int d = blockIdx.y * 256 + threadIdx.x;
    int bc = blockIdx.x;
    int b = bc >> 5, c = bc & 31;
    const float* Sp = S + (long)(b * NC) * Dd + d;
    float run = 0.f;
    for (int cc = 0; cc < c; ++cc) run += Sp[(long)cc * Dd];
    long row = (long)b * Tt + c * CT;
    for (int tt = 0; tt < CT; ++tt) {
        long r = row + tt;
        union { unsigned int u; float f; } cx;
        cx.u = ((unsigned int)Ginx[r * 4096 + d]) << 16;
        run += cx.f;
        float av = run / (float)(c * CT + tt + 1);
        AVG[r * Dd + d] = av;
        __hip_bfloat16 ab = __float2bfloat16(av);
        Gin[r * 4096 + 2048 + d] = *(unsigned short*)&ab;
    }
}

// ---------------- K4: 8-wave 256x(128d x 2 gates), 5-slot ring, BK=32/slot --
// R8's proven body at half-tile (BK=32) granularity on a 5-slot x 32KB ring
// (160KB = full LDS). Slot h stages slot h+4 (2 K-tiles ahead); ONE vmcnt(8)
// + ONE barrier per slot (same rate as R8's 2-per-BK64, but every wait is
// for >=3-slot-old loads -> never latency-blocks). Reads pipelined one slot
// ahead (R8 style). Slot layout [A0 8K][A1 8K][B0 8K][B1 8K]; proven swizzle.
// FIFO: entry {h+2,h+3}=8 in flight; +4 (h+4) -> 12; vmcnt(8) drains h+2.
// WAR: staging of h+4 targets region (h-1)%5, sealed by h-1's barrier.
#define MFMA(va, vb, c_) c_ = __builtin_amdgcn_mfma_f32_16x16x32_bf16(va, vb, c_, 0, 0, 0)
#define RD(p_, i_) (*(const bf16x8*)((p_) + (i_) * 1024))
#define SBAR __builtin_amdgcn_s_barrier()
#define SCHB __builtin_amdgcn_sched_barrier(0)
#define LGKM0 do { asm volatile("s_waitcnt lgkmcnt(0)" ::: "memory"); SCHB; } while (0)

#define CL_LO(B0_, B1_, B2_, B3_)                                               \
    __builtin_amdgcn_s_setprio(1);                                              \
    MFMA(aL0,B0_,acc[0][0]); MFMA(aL0,B1_,acc[0][1]); MFMA(aL0,B2_,acc[0][2]); MFMA(aL0,B3_,acc[0][3]); \
    MFMA(aL1,B0_,acc[1][0]); MFMA(aL1,B1_,acc[1][1]); MFMA(aL1,B2_,acc[1][2]); MFMA(aL1,B3_,acc[1][3]); \
    MFMA(aL2,B0_,acc[2][0]); MFMA(aL2,B1_,acc[2][1]); MFMA(aL2,B2_,acc[2][2]); MFMA(aL2,B3_,acc[2][3]); \
    MFMA(aL3,B0_,acc[3][0]); MFMA(aL3,B1_,acc[3][1]); MFMA(aL3,B2_,acc[3][2]); MFMA(aL3,B3_,acc[3][3]); \
    __builtin_amdgcn_s_setprio(0);
#define CL_HI(B0_, B1_, B2_, B3_)                                               \
    __builtin_amdgcn_s_setprio(1);                                              \
    MFMA(aH0,B0_,acc[4][0]); MFMA(aH0,B1_,acc[4][1]); MFMA(aH0,B2_,acc[4][2]); MFMA(aH0,B3_,acc[4][3]); \
    MFMA(aH1,B0_,acc[5][0]); MFMA(aH1,B1_,acc[5][1]); MFMA(aH1,B2_,acc[5][2]); MFMA(aH1,B3_,acc[5][3]); \
    MFMA(aH2,B0_,acc[6][0]); MFMA(aH2,B1_,acc[6][1]); MFMA(aH2,B2_,acc[6][2]); MFMA(aH2,B3_,acc[6][3]); \
    MFMA(aH3,B0_,acc[7][0]); MFMA(aH3,B1_,acc[7][1]); MFMA(aH3,B2_,acc[7][2]); MFMA(aH3,B3_,acc[7][3]); \
    __builtin_amdgcn_s_setprio(0);

// One BK=32 slot. sOFF: this slot; snOFF: next slot (read-prefetch source);
// stOFF: stage target region ((h+4)%5); t4_: staged slot index (K offset).
#define SLOT(sOFF_, snOFF_, stOFF_, t4_, B0_,B1_,B2_,B3_, N0_,N1_,N2_,N3_, STG_, RDX_, VN_) \
  {                                                                             \
    const char* pa_ = rA0 + (sOFF_);                                            \
    const char* qa_ = rA0 + (snOFF_);                                           \
    const char* qb_ = rB0 + (snOFF_);                                           \
    char* st_ = ldsb + (stOFF_) + woff;                                         \
    const long ko_ = (long)(t4_) * 64;                                          \
    LGKM0;                                      /* X(h) ready: aL + cur B */    \
    aH0 = RD(pa_,4); aH1 = RD(pa_,5); aH2 = RD(pa_,6); aH3 = RD(pa_,7);         \
    if (STG_) { gload16(gA0 + ko_, st_); gload16(gA1 + ko_, st_ + 8192); }      \
    SCHB;                                                                       \
    CL_LO(B0_, B1_, B2_, B3_)                                                   \
    SCHB;                                                                       \
    LGKM0;                                      /* Y(h) ready */                \
    if (RDX_) {                                                                 \
      aL0 = RD(qa_,0); aL1 = RD(qa_,1); aL2 = RD(qa_,2); aL3 = RD(qa_,3);       \
      N0_ = RD(qb_,0); N1_ = RD(qb_,1); N2_ = RD(qb_,2); N3_ = RD(qb_,3);       \
    }                                                                           \
    if (STG_) { gload16(gB0 + ko_, st_ + 16384); gload16(gB1 + ko_, st_ + 24576); } \
    SCHB;                                                                       \
    CL_HI(B0_, B1_, B2_, B3_)                                                   \
    SCHB;                                                                       \
    asm volatile("s_waitcnt vmcnt(" #VN_ ")" ::: "memory");                     \
    SBAR; SCHB;                                                                 \
  }

#define S0 0
#define S1 32768
#define S2 65536
#define S3 98304
#define S4 131072

__global__ __launch_bounds__(512, 1) void gemm5r_kernel(
    const unsigned short* __restrict__ Gin,  // [16384][4096] bf16
    const unsigned short* __restrict__ Wb,   // [4096][4096] bf16
    const float* __restrict__ bias,          // [4096]
    float* __restrict__ OUT)                 // [16384][2048]
{
    __shared__ __attribute__((aligned(128))) char lds[163840]; // 5 x 32KB ring
    char* ldsb = (char*)lds;

    const int tid = threadIdx.x;
    const int w = tid >> 6, l = tid & 63;
    const int wm = w >> 2, wn = w & 3;       // 2(M) x 4(N) waves
    const int lm = l & 15;
    const int woff = w * 1024;

    // Batch-aware mapping (FETCH-proven): 256-block rounds = 16 m-tiles x
    // 16 n-tiles (A 32MB + W 32MB < L3); per XCD 2 n-tiles (B panel -> L2).
    const int bid = blockIdx.x;
    const int batch = bid >> 8;
    const int rr = bid & 255;
    const int xcd = rr & 7;
    const int j = rr >> 3;
    const int nt = xcd * 2 + (j >> 4);
    const int mt = batch * 16 + (j & 15);
    const long m0 = (long)mt * 256;
    const int n0 = nt * 128;

    // ---- staging addresses (pre-swizzled global chunk; LDS dest linear) ----
    const int srow = tid >> 2;
    const int schunk = (tid & 3) ^ ((tid >> 3) & 3);
    const char* gA0 = (const char*)Gin + (m0 + srow) * 8192 + schunk * 16;
    const char* gA1 = gA0 + 128 * 8192;
    // B tile row j (0..255) -> W row: d-block (j>>6)*32 + (j&31), gate (j>>5)&1
    const long jr0 = n0 + ((srow >> 6) << 5) + (srow & 31) + (((srow >> 5) & 1) << 11);
    const int j1 = 128 + srow;
    const long jr1 = n0 + ((j1 >> 6) << 5) + (j1 & 31) + (((j1 >> 5) & 1) << 11);
    const char* gB0 = (const char*)Wb + jr0 * 8192 + schunk * 16;
    const char* gB1 = (const char*)Wb + jr1 * 8192 + schunk * 16;

    // ---- read addresses (proven 0-conflict swizzle) ----
    const int cbyte = (((l >> 4) ^ ((lm >> 1) & 3))) * 16;
    const char* rA0 = ldsb + (wm * 128 + lm) * 64 + cbyte;          // +slot +mi*1024
    const char* rB0 = ldsb + 16384 + (wn * 64 + lm) * 64 + cbyte;   // +slot +nj*1024

    f32x4 acc[8][4] = {};   // [mi][nj]: nj 0-1 gate-i, 2-3 gate-f

    // rotating operand registers: aL/aH shared; bb = even slots, bd = odd
    bf16x8 aL0, aL1, aL2, aL3, aH0, aH1, aH2, aH3;
    bf16x8 bb0, bb1, bb2, bb3, bd0, bd1, bd2, bd3;

    // prologue: stage slots 0..3 (16 loads); slots 0,1 drained; X(0) reads
    gload16(gA0,       ldsb + S0 + woff);
    gload16(gA1,       ldsb + S0 + 8192 + woff);
    gload16(gB0,       ldsb + S0 + 16384 + woff);
    gload16(gB1,       ldsb + S0 + 24576 + woff);
    gload16(gA0 + 64,  ldsb + S1 + woff);
    gload16(gA1 + 64,  ldsb + S1 + 8192 + woff);
    gload16(gB0 + 64,  ldsb + S1 + 16384 + woff);
    gload16(gB1 + 64,  ldsb + S1 + 24576 + woff);
    gload16(gA0 + 128, ldsb + S2 + woff);
    gload16(gA1 + 128, ldsb + S2 + 8192 + woff);
    gload16(gB0 + 128, ldsb + S2 + 16384 + woff);
    gload16(gB1 + 128, ldsb + S2 + 24576 + woff);
    gload16(gA0 + 192, ldsb + S3 + woff);
    gload16(gA1 + 192, ldsb + S3 + 8192 + woff);
    gload16(gB0 + 192, ldsb + S3 + 16384 + woff);
    gload16(gB1 + 192, ldsb + S3 + 24576 + woff);
    asm volatile("s_waitcnt vmcnt(8)" ::: "memory");   // slots 0,1 landed
    SBAR; SCHB;
    aL0 = RD(rA0,0); aL1 = RD(rA0,1); aL2 = RD(rA0,2); aL3 = RD(rA0,3);
    bb0 = RD(rB0,0); bb1 = RD(rB0,1); bb2 = RD(rB0,2); bb3 = RD(rB0,3);
    SCHB;

#pragma unroll 1
    for (int t = 0; t < 120; t += 10) {   // slots t..t+9, stage t+4..t+13
        SLOT(S0,S1,S4, t+4,  bb0,bb1,bb2,bb3, bd0,bd1,bd2,bd3, 1,1,8)
        SLOT(S1,S2,S0, t+5,  bd0,bd1,bd2,bd3, bb0,bb1,bb2,bb3, 1,1,8)
        SLOT(S2,S3,S1, t+6,  bb0,bb1,bb2,bb3, bd0,bd1,bd2,bd3, 1,1,8)
        SLOT(S3,S4,S2, t+7,  bd0,bd1,bd2,bd3, bb0,bb1,bb2,bb3, 1,1,8)
        SLOT(S4,S0,S3, t+8,  bb0,bb1,bb2,bb3, bd0,bd1,bd2,bd3, 1,1,8)
        SLOT(S0,S1,S4, t+9,  bd0,bd1,bd2,bd3, bb0,bb1,bb2,bb3, 1,1,8)
        SLOT(S1,S2,S0, t+10, bb0,bb1,bb2,bb3, bd0,bd1,bd2,bd3, 1,1,8)
        SLOT(S2,S3,S1, t+11, bd0,bd1,bd2,bd3, bb0,bb1,bb2,bb3, 1,1,8)
        SLOT(S3,S4,S2, t+12, bb0,bb1,bb2,bb3, bd0,bd1,bd2,bd3, 1,1,8)
        SLOT(S4,S0,S3, t+13, bd0,bd1,bd2,bd3, bb0,bb1,bb2,bb3, 1,1,8)
    }
    // tail: slots 120..127 (120..123 stage 124..127; then drain)
    SLOT(S0,S1,S4, 124, bb0,bb1,bb2,bb3, bd0,bd1,bd2,bd3, 1,1,8)
    SLOT(S1,S2,S0, 125, bd0,bd1,bd2,bd3, bb0,bb1,bb2,bb3, 1,1,8)
    SLOT(S2,S3,S1, 126, bb0,bb1,bb2,bb3, bd0,bd1,bd2,bd3, 1,1,8)
    SLOT(S3,S4,S2, 127, bd0,bd1,bd2,bd3, bb0,bb1,bb2,bb3, 1,1,8)
    SLOT(S4,S0,S3, 0,   bb0,bb1,bb2,bb3, bd0,bd1,bd2,bd3, 0,1,4)
    SLOT(S0,S1,S4, 0,   bd0,bd1,bd2,bd3, bb0,bb1,bb2,bb3, 0,1,0)
    SLOT(S1,S2,S0, 0,   bb0,bb1,bb2,bb3, bd0,bd1,bd2,bd3, 0,1,0)
    SLOT(S2,S3,S1, 0,   bd0,bd1,bd2,bd3, bb0,bb1,bb2,bb3, 0,0,0)

    // ---- fused epilogue (bf16 x/avg from Gin; C/D: col=l&15, row=(l>>4)*4+r)
#pragma unroll
    for (int mi = 0; mi < 8; ++mi) {
        long rbase = m0 + wm * 128 + mi * 16 + (l >> 4) * 4;
#pragma unroll
        for (int nj = 0; nj < 2; ++nj) {
            int d = n0 + wn * 32 + nj * 16 + lm;
            float bi_ = bias[d];
            float bf_ = bias[d + 2048];
#pragma unroll
            for (int r = 0; r < 4; ++r) {
                long row = rbase + r;
                unsigned int ux = Gin[row * 4096 + d];
                unsigned int ua = Gin[row * 4096 + 2048 + d];
                union { unsigned int u; float f; } cx, ca;
                cx.u = ux << 16; ca.u = ua << 16;
                float gi = acc[mi][nj][r] + bi_;
                float gf = acc[mi][nj + 2][r] + bf_;
                float si = 1.f / (1.f + __expf(-gi));
                float sf = 1.f / (1.f + __expf(-gf));
                OUT[row * 2048 + d] = si * cx.f + sf * ca.f;
            }
        }
    }
}

extern "C" void kernel_launch(void* const* d_in, const int* in_sizes, int n_in,
                              void* d_out, int out_size, void* d_ws, size_t ws_size,
                              hipStream_t stream) {
    const float* X = (const float*)d_in[0];     // layer_in [8][2048][2048]
    const float* W = (const float*)d_in[1];     // W_gate [4096][4096]
    const float* bias = (const float*)d_in[2];  // b_gate [4096]

    float* OUT = (float*)d_out;                 // gating_out
    float* AVG = OUT + (long)Mm * Dd;           // average_out

    char* ws = (char*)d_ws;
    unsigned short* Wb  = (unsigned short*)ws;                    // 33,554,432 B
    unsigned short* Gin = (unsigned short*)(ws + 33554432);       // 134,217,728 B
    float* S = (float*)(ws + 33554432 + 134217728);               // 2,097,152 B

    wconv_kernel<<<2048, 256, 0, stream>>>(W, Wb, (long)Kk * Kk);
    ksum_kernel<<<dim3(Bb * NC, Dd / 256), 256, 0, stream>>>(X, S, Gin);
    kscan_kernel<<<dim3(Bb * NC, Dd / 256), 256, 0, stream>>>(Gin, S, AVG, Gin);
    gemm5r_kernel<<<1024, 512, 0, stream>>>(Gin, Wb, bias, OUT);
}